// Round 14
// baseline (265.980 us; speedup 1.0000x reference)
//
#include <hip/hip_runtime.h>

#define DI __device__ __forceinline__

typedef float f4 __attribute__((ext_vector_type(4)));
typedef float f2 __attribute__((ext_vector_type(2)));
typedef unsigned short u16x8 __attribute__((ext_vector_type(8)));
typedef unsigned short u16x4 __attribute__((ext_vector_type(4)));
typedef __bf16 bf16x8 __attribute__((ext_vector_type(8)));
typedef float f32x4 __attribute__((ext_vector_type(4)));

constexpr int C = 256;
constexpr int N = 2048;
constexpr int BN = 16 * 2048;   // 32768 points total

DI float bf2f(unsigned short h){
  union { unsigned int u; float f; } v; v.u = ((unsigned int)h) << 16; return v.f;
}
DI unsigned short f2bf(float f){
  union { float f; unsigned int u; } v; v.f = f;
  unsigned int r = v.u + 0x7fffu + ((v.u >> 16) & 1u);   // RNE
  return (unsigned short)(r >> 16);
}
DI unsigned int f2u(float f){ union { float f; unsigned int u; } v; v.f = f; return v.u; }
DI float u2f(unsigned int u){ union { unsigned int u; float f; } v; v.u = u; return v.f; }

// top-3 insert, tie -> lower index (matches lax.top_k set semantics)
DI void ins3(float v, int n, float& v0, float& v1, float& v2, int& i0, int& i1, int& i2){
  bool b0 = (v > v0) || (v == v0 && n < i0);
  bool b1 = (v > v1) || (v == v1 && n < i1);
  bool b2 = (v > v2) || (v == v2 && n < i2);
  if (b0){ v2=v1; i2=i1; v1=v0; i1=i0; v0=v; i0=n; }
  else if (b1){ v2=v1; i2=i1; v1=v; i1=n; }
  else if (b2){ v2=v; i2=n; }
}

DI void gload16(const void* g, void* l){
  __builtin_amdgcn_global_load_lds(
      (const __attribute__((address_space(1))) unsigned int*)g,
      (__attribute__((address_space(3))) unsigned int*)l, 16, 0, 0);
}

// ---------- k_cvt: x (B,C,N) fp32 -> xT (BN,256) fp32, xhT (BN,256) bf16, sq4[p][4] partials ----------
__global__ __launch_bounds__(256) void k_cvt(const float* __restrict__ x,
    unsigned short* __restrict__ xhT, float* __restrict__ xT, float* __restrict__ sq4)
{
  __shared__ float T[64][68];
  int bid = blockIdx.x;
  int pt = bid & 31, ct = (bid >> 5) & 3, b = bid >> 7;
  int p0 = pt * 64, c0 = ct * 64;
  int tid = threadIdx.x;
  int cr = tid >> 4, cv = tid & 15;
  const float* xb = x + ((size_t)b * C + c0) * N + p0;
  #pragma unroll
  for (int i = 0; i < 4; i++){
    int c = cr + i * 16;
    f4 v = *(const f4*)(xb + (size_t)c * N + cv * 4);
    T[cv*4+0][c] = v[0]; T[cv*4+1][c] = v[1]; T[cv*4+2][c] = v[2]; T[cv*4+3][c] = v[3];
  }
  __syncthreads();
  int p = tid >> 2, cq = tid & 3;
  size_t rowg = (size_t)b * N + p0 + p;
  float* xtr = xT + rowg * 256 + c0 + cq * 16;
  unsigned short* xhr = xhT + rowg * 256 + c0 + cq * 16;
  float sacc = 0.f;
  #pragma unroll
  for (int j = 0; j < 4; j++){
    f4 v = *(const f4*)&T[p][cq*16 + j*4];
    *(f4*)(xtr + j*4) = v;
    sacc += (v[0]*v[0] + v[1]*v[1]) + (v[2]*v[2] + v[3]*v[3]);
    u16x4 h; h[0]=f2bf(v[0]); h[1]=f2bf(v[1]); h[2]=f2bf(v[2]); h[3]=f2bf(v[3]);
    *(u16x4*)(xhr + j*4) = h;
  }
  sacc += __shfl_xor(sacc, 1, 64);
  sacc += __shfl_xor(sacc, 2, 64);
  if (cq == 0) sq4[rowg * 4 + ct] = sacc;
}

// ---------- k_pd v9: 32-row blocks, af[2][8] register-resident (asm-pinned), double-buffered B ----------
// LDS: [0,32K) = 4 waves x 2 x 4KB B tiles; [32K,48K) = A tile 16KB. Merge overlays [0,27KB).
__global__ __launch_bounds__(256, 3) void k_pd(const unsigned short* __restrict__ xhT,
    const float* __restrict__ sq4, int* __restrict__ idx8)
{
  __shared__ __align__(16) char sm[49152];
  int wg = blockIdx.x;
  int wid = (wg & 7) * 128 + (wg >> 3);   // XCD chunk swizzle: 1024 blocks, 2 batches/XCD
  int b = wid >> 6, mt = wid & 63;
  int m0 = mt * 32;
  int tid = threadIdx.x, w = tid >> 6, l = tid & 63;
  const unsigned short* xb = xhT + (size_t)b * N * 256;
  const float* sqb4 = sq4 + (size_t)b * N * 4;
  char* Ab = sm + 32768;          // A tile (16KB)
  char* wbuf = sm + w * 8192;     // this wave's 2 B buffers

  // stage A cooperatively: 32 rows x 256k bf16 = 1024 chunks (4/thread)
  #pragma unroll
  for (int i = 0; i < 4; i++){
    int flat = i * 256 + tid;
    int m = flat >> 5, c = flat & 31;
    gload16(xb + (size_t)(m0 + m) * 256 + ((c ^ (m & 7)) << 3), Ab + flat * 16);
  }
  // per-wave B prefetch: tile 0 only (double buffer)
  #pragma unroll
  for (int i = 0; i < 4; i++){
    int p = i * 4 + (l >> 4), c = l & 15;
    gload16(xb + (size_t)(w * 16 + p) * 256 + ((c ^ (p & 7)) << 3),
            wbuf + (i * 64 + l) * 16);
  }
  asm volatile("s_waitcnt vmcnt(4)" ::: "memory");   // A complete; B0 in flight
  __builtin_amdgcn_s_barrier();

  // A fragments -> registers, pinned (prevents LDS-remat: the R9/R13 67us LDS-read wall)
  bf16x8 af[2][8];
  #pragma unroll
  for (int rt = 0; rt < 2; rt++)
    #pragma unroll
    for (int ks = 0; ks < 8; ks++){
      int m = rt * 16 + (l & 15);
      int ch = ks * 4 + (l >> 4);
      af[rt][ks] = *(const bf16x8*)(Ab + m * 512 + ((ch ^ (m & 7)) << 4));
      asm volatile("" : "+v"(af[rt][ks]));
    }

  float K[8][3];
  #pragma unroll
  for (int a = 0; a < 8; a++){ K[a][0] = 0.f; K[a][1] = 0.f; K[a][2] = 0.f; }

  f32x4 acc[2];
  for (int it = 0; it < 64; it++){
    if (it + 1 < 64){
      int nx = it + 1;
      int P0 = (nx >> 1) * 64, kh2 = nx & 1;
      char* dst = wbuf + (nx & 1) * 4096;
      #pragma unroll
      for (int i = 0; i < 4; i++){
        int p = i * 4 + (l >> 4), c = l & 15;
        gload16(xb + (size_t)(P0 + w * 16 + p) * 256 + kh2 * 128 + ((c ^ (p & 7)) << 3),
                dst + (i * 64 + l) * 16);
      }
      asm volatile("s_waitcnt vmcnt(4)" ::: "memory");   // tile `it` landed
    } else {
      asm volatile("s_waitcnt vmcnt(0)" ::: "memory");
    }

    const char* bb = wbuf + (it & 1) * 4096;
    int kh = it & 1;
    if (kh == 0){
      f32x4 z = {0.f, 0.f, 0.f, 0.f};
      acc[0] = z; acc[1] = z;
    }
    #pragma unroll
    for (int ks = 0; ks < 4; ks++){
      int p = l & 15;
      int ch = ks * 4 + (l >> 4);
      bf16x8 bv = *(const bf16x8*)(bb + p * 256 + ((ch ^ (p & 7)) << 4));
      if (kh == 0){
        acc[0] = __builtin_amdgcn_mfma_f32_16x16x32_bf16(af[0][ks], bv, acc[0], 0, 0, 0);
        acc[1] = __builtin_amdgcn_mfma_f32_16x16x32_bf16(af[1][ks], bv, acc[1], 0, 0, 0);
      } else {
        acc[0] = __builtin_amdgcn_mfma_f32_16x16x32_bf16(af[0][4 + ks], bv, acc[0], 0, 0, 0);
        acc[1] = __builtin_amdgcn_mfma_f32_16x16x32_bf16(af[1][4 + ks], bv, acc[1], 0, 0, 0);
      }
    }
    if (kh == 1){
      int col = (it >> 1) * 64 + w * 16 + (l & 15);
      f4 s4 = *(const f4*)(sqb4 + (size_t)col * 4);
      float nb = 1024.f - ((s4[0] + s4[1]) + (s4[2] + s4[3]));
      unsigned int ib = (unsigned int)(2047 - col);
      #pragma unroll
      for (int rt = 0; rt < 2; rt++)
        #pragma unroll
        for (int r = 0; r < 4; r++){
          float v = fmaf(acc[rt][r], 2.f, nb);
          float key = u2f((f2u(v) & 0xFFFFF800u) | ib);
          int a = rt * 4 + r;
          K[a][2] = __builtin_amdgcn_fmed3f(K[a][1], K[a][2], key);
          K[a][1] = __builtin_amdgcn_fmed3f(K[a][0], K[a][1], key);
          K[a][0] = fmaxf(K[a][0], key);
        }
    }
  }
  __syncthreads();   // all waves done with B buffers & A reads; overlay merge scratch
  // merge: 32 rows x 192 keys, stride 193 words
  float* mK = (float*)sm;
  #pragma unroll
  for (int rt = 0; rt < 2; rt++)
    #pragma unroll
    for (int r = 0; r < 4; r++){
      int row = rt * 16 + (l >> 4) * 4 + r;
      int base = row * 193 + w * 48 + (l & 15) * 3;
      mK[base+0] = K[rt*4+r][0]; mK[base+1] = K[rt*4+r][1]; mK[base+2] = K[rt*4+r][2];
    }
  __syncthreads();
  float* aux = (float*)(sm + 24704);   // after 32*193*4 B; stride 17 words (2176 B)
  if (tid < 128){
    int row = tid >> 2, q = tid & 3;
    float t0 = 0.f, t1 = 0.f, t2 = 0.f, t3 = 0.f;
    const float* src = mK + row * 193 + q * 48;
    for (int s = 0; s < 48; s++){
      float v = src[s];
      t3 = __builtin_amdgcn_fmed3f(t2, t3, v);
      t2 = __builtin_amdgcn_fmed3f(t1, t2, v);
      t1 = __builtin_amdgcn_fmed3f(t0, t1, v);
      t0 = fmaxf(t0, v);
    }
    float* d = aux + row * 17 + q * 4;
    d[0] = t0; d[1] = t1; d[2] = t2; d[3] = t3;
  }
  __syncthreads();
  if (tid < 32){
    float u0=0.f,u1=0.f,u2=0.f,u3=0.f,u4=0.f,u5=0.f,u6=0.f,u7=0.f;
    const float* srcp = aux + tid * 17;
    #pragma unroll
    for (int s = 0; s < 16; s++){
      float v = srcp[s];
      u7 = __builtin_amdgcn_fmed3f(u6, u7, v);
      u6 = __builtin_amdgcn_fmed3f(u5, u6, v);
      u5 = __builtin_amdgcn_fmed3f(u4, u5, v);
      u4 = __builtin_amdgcn_fmed3f(u3, u4, v);
      u3 = __builtin_amdgcn_fmed3f(u2, u3, v);
      u2 = __builtin_amdgcn_fmed3f(u1, u2, v);
      u1 = __builtin_amdgcn_fmed3f(u0, u1, v);
      u0 = fmaxf(u0, v);
    }
    int* d = idx8 + ((size_t)(b * N + m0 + tid)) * 8;
    d[0]=2047-(int)(f2u(u0)&2047u); d[1]=2047-(int)(f2u(u1)&2047u);
    d[2]=2047-(int)(f2u(u2)&2047u); d[3]=2047-(int)(f2u(u3)&2047u);
    d[4]=2047-(int)(f2u(u4)&2047u); d[5]=2047-(int)(f2u(u5)&2047u);
    d[6]=2047-(int)(f2u(u6)&2047u); d[7]=2047-(int)(f2u(u7)&2047u);
  }
}

// ---------- k_rerank: exact fp32 pd over 8 candidates, pair-parallel (2 rows/wave) ----------
__global__ __launch_bounds__(256) void k_rerank(const float* __restrict__ xT,
    const float* __restrict__ sq4, const int* __restrict__ idx8, int* __restrict__ idx3)
{
  int w = threadIdx.x >> 6, l = threadIdx.x & 63;
  int h = l >> 5, lh = l & 31;
  int wv = blockIdx.x * 4 + w;
  #pragma unroll
  for (int rr = 0; rr < 2; rr++){
    int row = wv * 2 + rr;
    int b = row >> 11;
    const float* xm = xT + (size_t)row * 256 + lh * 8;
    f4 xm0 = *(const f4*)xm;
    f4 xm1 = *(const f4*)(xm + 4);
    const int* cb = idx8 + (size_t)row * 8;
    int nn[8];
    #pragma unroll
    for (int c2 = 0; c2 < 8; c2++) nn[c2] = cb[c2];
    f4 a0[4], a1[4];
    #pragma unroll
    for (int j = 0; j < 4; j++){
      int n = nn[2*j + h];
      const float* xn = xT + ((size_t)(b * N + n)) * 256 + lh * 8;
      a0[j] = *(const f4*)xn;
      a1[j] = *(const f4*)(xn + 4);
    }
    float v0=-3e38f, v1=v0, v2=v0; int i0=0x7fffffff, i1=i0, i2=i0;
    #pragma unroll
    for (int j = 0; j < 4; j++){
      float s = ((xm0[0]*a0[j][0] + xm0[1]*a0[j][1]) + (xm0[2]*a0[j][2] + xm0[3]*a0[j][3]))
              + ((xm1[0]*a1[j][0] + xm1[1]*a1[j][1]) + (xm1[2]*a1[j][2] + xm1[3]*a1[j][3]));
      #pragma unroll
      for (int d = 1; d < 32; d <<= 1) s += __shfl_xor(s, d, 64);
      float so = __shfl_xor(s, 32, 64);
      float pe = h ? so : s;
      float po = h ? s : so;
      int ne = nn[2*j], no = nn[2*j+1];
      f4 s4e = *(const f4*)(sq4 + ((size_t)(b * N + ne)) * 4);
      f4 s4o = *(const f4*)(sq4 + ((size_t)(b * N + no)) * 4);
      float ve = 2.f * pe - ((s4e[0] + s4e[1]) + (s4e[2] + s4e[3]));
      float vo = 2.f * po - ((s4o[0] + s4o[1]) + (s4o[2] + s4o[3]));
      ins3(ve, ne, v0, v1, v2, i0, i1, i2);
      ins3(vo, no, v0, v1, v2, i0, i1, i2);
    }
    if (l == 0){
      size_t ob = (size_t)row * 3;
      idx3[ob] = i0; idx3[ob+1] = i1; idx3[ob+2] = i2;
    }
  }
}

// ---------- k_ut1 (MFMA): rows 0..255 -> u (Ws1 halves), 256..383 -> t1=relu(Wt1 x + bt1) ----------
__global__ __launch_bounds__(256, 2) void k_ut1(const float* __restrict__ Ws1,
    const float* __restrict__ Wt1, const float* __restrict__ bt1,
    const unsigned short* __restrict__ xhT,
    unsigned short* __restrict__ u_ws, unsigned short* __restrict__ t1_ws)
{
  __shared__ __align__(16) unsigned short A[64 * 256];
  int wg = blockIdx.x;
  int wid = (wg & 7) * 96 + (wg >> 3);
  int mb = wid % 6, pt = wid / 6;
  int m0 = mb * 64, p0 = pt * 256;
  int tid = threadIdx.x, w = tid >> 6, l = tid & 63;
  #pragma unroll
  for (int i = 0; i < 8; i++){
    int flat = i * 256 + tid;
    int m = flat >> 5, c = flat & 31;
    int mg = m0 + m;
    const float* srcp;
    if (mg < 128)      srcp = Ws1 + (size_t)mg * 512 + c * 8;
    else if (mg < 256) srcp = Ws1 + (size_t)(mg - 128) * 512 + 256 + c * 8;
    else               srcp = Wt1 + (size_t)(mg - 256) * 256 + c * 8;
    f4 v0 = *(const f4*)srcp, v1 = *(const f4*)(srcp + 4);
    u16x8 h;
    h[0]=f2bf(v0[0]); h[1]=f2bf(v0[1]); h[2]=f2bf(v0[2]); h[3]=f2bf(v0[3]);
    h[4]=f2bf(v1[0]); h[5]=f2bf(v1[1]); h[6]=f2bf(v1[2]); h[7]=f2bf(v1[3]);
    *(u16x8*)(A + m * 256 + ((c ^ (m & 7)) << 3)) = h;
  }
  __syncthreads();
  bf16x8 af[4][8];
  #pragma unroll
  for (int rt = 0; rt < 4; rt++)
    #pragma unroll
    for (int ks = 0; ks < 8; ks++){
      int m = rt * 16 + (l & 15);
      int ch = ks * 4 + (l >> 4);
      af[rt][ks] = *(const bf16x8*)((const char*)A + m * 512 + ((ch ^ (m & 7)) << 4));
    }
  bool isU = (m0 < 256);
  f4 bias[4];
  if (!isU){
    #pragma unroll
    for (int rt = 0; rt < 4; rt++)
      bias[rt] = *(const f4*)(bt1 + (m0 - 256) + rt * 16 + (l >> 4) * 4);
  }
  for (int ct = 0; ct < 4; ct++){
    int p = p0 + ct * 64 + w * 16 + (l & 15);
    const unsigned short* bp = xhT + (size_t)p * 256 + (l >> 4) * 8;
    f32x4 acc[4];
    f32x4 z = {0.f, 0.f, 0.f, 0.f};
    #pragma unroll
    for (int rt = 0; rt < 4; rt++) acc[rt] = z;
    #pragma unroll
    for (int ks = 0; ks < 8; ks++){
      bf16x8 bv = *(const bf16x8*)(bp + ks * 32);
      #pragma unroll
      for (int rt = 0; rt < 4; rt++)
        acc[rt] = __builtin_amdgcn_mfma_f32_16x16x32_bf16(af[rt][ks], bv, acc[rt], 0, 0, 0);
    }
    if (isU){
      #pragma unroll
      for (int rt = 0; rt < 4; rt++){
        u16x4 h;
        h[0]=f2bf(acc[rt][0]); h[1]=f2bf(acc[rt][1]); h[2]=f2bf(acc[rt][2]); h[3]=f2bf(acc[rt][3]);
        *(u16x4*)(u_ws + (size_t)p * 256 + m0 + rt * 16 + (l >> 4) * 4) = h;
      }
    } else {
      #pragma unroll
      for (int rt = 0; rt < 4; rt++){
        u16x4 h;
        h[0]=f2bf(fmaxf(acc[rt][0] + bias[rt][0], 0.f));
        h[1]=f2bf(fmaxf(acc[rt][1] + bias[rt][1], 0.f));
        h[2]=f2bf(fmaxf(acc[rt][2] + bias[rt][2], 0.f));
        h[3]=f2bf(fmaxf(acc[rt][3] + bias[rt][3], 0.f));
        *(u16x4*)(t1_ws + (size_t)p * 128 + (m0 - 256) + rt * 16 + (l >> 4) * 4) = h;
      }
    }
  }
}

// ---------- k_te (fused independent): blocks 0..511 = t2 grouped conv; 512..1023 = e1 gather+s1+s2 ----------
__global__ __launch_bounds__(256) void k_te(const unsigned short* __restrict__ t1_ws,
    const float* __restrict__ Wt2, const float* __restrict__ bt2,
    unsigned short* __restrict__ t2_ws,
    const unsigned short* __restrict__ u_ws, const int* __restrict__ idx_ws,
    const float* __restrict__ bs1, const float* __restrict__ Ws2,
    const float* __restrict__ bs2, unsigned short* __restrict__ s2_ws)
{
  __shared__ float w2[1536];
  __shared__ float b2[128];
  __shared__ float sb1[128], sb2[128], sw2[512];
  int tid = threadIdx.x;
  if (blockIdx.x < 512){
    for (int i = tid; i < 1536; i += 256) w2[i] = Wt2[i];
    if (tid < 128) b2[tid] = bt2[tid];
    __syncthreads();
    int p = blockIdx.x * 64 + (tid >> 2);
    int q = tid & 3;
    int n = p & (N - 1);
    const unsigned short* rp = t1_ws + (size_t)p * 128;
    u16x8 zz = {0,0,0,0,0,0,0,0};
    #pragma unroll
    for (int g8 = 0; g8 < 4; g8++){
      int ch0 = q*32 + g8*8;
      u16x8 vm1 = (n > 0)     ? *(const u16x8*)(rp - 128 + ch0) : zz;
      u16x8 v0  =               *(const u16x8*)(rp + ch0);
      u16x8 vp1 = (n < N - 1) ? *(const u16x8*)(rp + 128 + ch0) : zz;
      float fm1[8], f0[8], fp1[8];
      #pragma unroll
      for (int e = 0; e < 8; e++){ fm1[e]=bf2f(vm1[e]); f0[e]=bf2f(v0[e]); fp1[e]=bf2f(vp1[e]); }
      u16x8 o;
      #pragma unroll
      for (int j = 0; j < 8; j++){
        int wch = ch0 + j, gb = j & ~3;
        float acc = b2[wch];
        #pragma unroll
        for (int i = 0; i < 4; i++){
          acc += w2[wch*12 + i*3 + 0] * fm1[gb + i];
          acc += w2[wch*12 + i*3 + 1] * f0[gb + i];
          acc += w2[wch*12 + i*3 + 2] * fp1[gb + i];
        }
        o[j] = f2bf(fmaxf(acc, 0.f));
      }
      *(u16x8*)(t2_ws + (size_t)p * 128 + ch0) = o;
    }
  } else {
    if (tid < 128){ sb1[tid] = bs1[tid]; sb2[tid] = bs2[tid]; }
    sw2[tid] = Ws2[tid]; sw2[tid+256] = Ws2[tid+256];
    __syncthreads();
    int p0 = (blockIdx.x - 512) * 64;
    #pragma unroll
    for (int rep = 0; rep < 3; rep++){
      int task = rep*256 + tid;
      int r = task >> 2, q = task & 3;
      int pl = r / 3, k = r - pl*3;
      int p = p0 + pl;
      int b = p >> 11;
      int m = idx_ws[(size_t)p*3 + k] & (N - 1);
      const unsigned short* ua = u_ws + ((size_t)(b*N + m))*256 + q*32;
      const unsigned short* ub = u_ws + ((size_t)p)*256 + 128 + q*32;
      float s1v[32];
      #pragma unroll
      for (int jj = 0; jj < 4; jj++){
        u16x8 a  = *(const u16x8*)(ua + jj*8);
        u16x8 cbv = *(const u16x8*)(ub + jj*8);
        #pragma unroll
        for (int e = 0; e < 8; e++){
          int j = jj*8 + e;
          s1v[j] = fmaxf(bf2f(a[e]) + bf2f(cbv[e]) + sb1[q*32 + j], 0.f);
        }
      }
      #pragma unroll
      for (int jj = 0; jj < 4; jj++){
        u16x8 o;
        #pragma unroll
        for (int e = 0; e < 8; e++){
          int j = jj*8 + e;
          int ch = q*32 + j, gb = j & ~3;
          float a2 = sb2[ch] + sw2[ch*4+0]*s1v[gb]   + sw2[ch*4+1]*s1v[gb+1]
                             + sw2[ch*4+2]*s1v[gb+2] + sw2[ch*4+3]*s1v[gb+3];
          o[e] = f2bf(fmaxf(a2, 0.f));
        }
        *(u16x8*)(s2_ws + ((size_t)k * BN + p) * 128 + q*32 + jj*8) = o;
      }
    }
  }
}

// ---------- k_e2f (fused): s3_k = Ws3.s2_k, tout = Wt3.t2 ; out = relu(max_k(s3)+bs3 + tout+bt3 + x) ----------
__global__ __launch_bounds__(256, 2) void k_e2f(const unsigned short* __restrict__ s2_ws,
    const unsigned short* __restrict__ t2_ws,
    const float* __restrict__ Ws3, const float* __restrict__ bs3,
    const float* __restrict__ Wt3, const float* __restrict__ bt3,
    const float* __restrict__ x, float* __restrict__ out)
{
  __shared__ __align__(16) unsigned short As[64 * 128];
  __shared__ __align__(16) unsigned short At[64 * 128];
  int wg = blockIdx.x;
  int wid = (wg & 7) * 64 + (wg >> 3);
  int mb = wid & 3, pt = wid >> 2;
  int m0 = mb * 64, p0 = pt * 256;
  int tid = threadIdx.x, w = tid >> 6, l = tid & 63;
  #pragma unroll
  for (int i = 0; i < 4; i++){
    int flat = i * 256 + tid;
    int m = flat >> 4, c = flat & 15;
    {
      const float* srcp = Ws3 + (size_t)(m0 + m) * 128 + c * 8;
      f4 v0 = *(const f4*)srcp, v1 = *(const f4*)(srcp + 4);
      u16x8 h;
      h[0]=f2bf(v0[0]); h[1]=f2bf(v0[1]); h[2]=f2bf(v0[2]); h[3]=f2bf(v0[3]);
      h[4]=f2bf(v1[0]); h[5]=f2bf(v1[1]); h[6]=f2bf(v1[2]); h[7]=f2bf(v1[3]);
      *(u16x8*)(As + m * 128 + ((c ^ (m & 7)) << 3)) = h;
    }
    {
      const float* srcp = Wt3 + (size_t)(m0 + m) * 128 + c * 8;
      f4 v0 = *(const f4*)srcp, v1 = *(const f4*)(srcp + 4);
      u16x8 h;
      h[0]=f2bf(v0[0]); h[1]=f2bf(v0[1]); h[2]=f2bf(v0[2]); h[3]=f2bf(v0[3]);
      h[4]=f2bf(v1[0]); h[5]=f2bf(v1[1]); h[6]=f2bf(v1[2]); h[7]=f2bf(v1[3]);
      *(u16x8*)(At + m * 128 + ((c ^ (m & 7)) << 3)) = h;
    }
  }
  __syncthreads();
  bf16x8 afs[4][4], aft[4][4];
  #pragma unroll
  for (int rt = 0; rt < 4; rt++)
    #pragma unroll
    for (int ks = 0; ks < 4; ks++){
      int m = rt * 16 + (l & 15);
      int ch = ks * 4 + (l >> 4);
      afs[rt][ks] = *(const bf16x8*)((const char*)As + m * 256 + ((ch ^ (m & 7)) << 4));
      aft[rt][ks] = *(const bf16x8*)((const char*)At + m * 256 + ((ch ^ (m & 7)) << 4));
    }
  f4 biasS[4], biasT[4];
  #pragma unroll
  for (int rt = 0; rt < 4; rt++){
    biasS[rt] = *(const f4*)(bs3 + m0 + rt * 16 + (l >> 4) * 4);
    biasT[rt] = *(const f4*)(bt3 + m0 + rt * 16 + (l >> 4) * 4);
  }
  for (int ct = 0; ct < 4; ct++){
    int p = p0 + ct * 64 + w * 16 + (l & 15);
    int b = p >> 11, n = p & (N - 1);
    const unsigned short* bp0 = s2_ws + ((size_t)(0 * BN + p)) * 128 + (l >> 4) * 8;
    const unsigned short* bp1 = s2_ws + ((size_t)(1 * BN + p)) * 128 + (l >> 4) * 8;
    const unsigned short* bp2 = s2_ws + ((size_t)(2 * BN + p)) * 128 + (l >> 4) * 8;
    const unsigned short* bpt = t2_ws + ((size_t)p) * 128 + (l >> 4) * 8;
    f32x4 acc[4][4];
    f32x4 z = {0.f, 0.f, 0.f, 0.f};
    #pragma unroll
    for (int rt = 0; rt < 4; rt++){ acc[rt][0]=z; acc[rt][1]=z; acc[rt][2]=z; acc[rt][3]=z; }
    #pragma unroll
    for (int ks = 0; ks < 4; ks++){
      bf16x8 bv0 = *(const bf16x8*)(bp0 + ks * 32);
      bf16x8 bv1 = *(const bf16x8*)(bp1 + ks * 32);
      bf16x8 bv2 = *(const bf16x8*)(bp2 + ks * 32);
      bf16x8 bvt = *(const bf16x8*)(bpt + ks * 32);
      #pragma unroll
      for (int rt = 0; rt < 4; rt++){
        acc[rt][0] = __builtin_amdgcn_mfma_f32_16x16x32_bf16(afs[rt][ks], bv0, acc[rt][0], 0, 0, 0);
        acc[rt][1] = __builtin_amdgcn_mfma_f32_16x16x32_bf16(afs[rt][ks], bv1, acc[rt][1], 0, 0, 0);
        acc[rt][2] = __builtin_amdgcn_mfma_f32_16x16x32_bf16(afs[rt][ks], bv2, acc[rt][2], 0, 0, 0);
        acc[rt][3] = __builtin_amdgcn_mfma_f32_16x16x32_bf16(aft[rt][ks], bvt, acc[rt][3], 0, 0, 0);
      }
    }
    #pragma unroll
    for (int rt = 0; rt < 4; rt++){
      int mbase = m0 + rt * 16 + (l >> 4) * 4;
      #pragma unroll
      for (int r = 0; r < 4; r++){
        float sout = fmaxf(fmaxf(acc[rt][0][r], acc[rt][1][r]), acc[rt][2][r]) + biasS[rt][r];
        float tout = acc[rt][3][r] + biasT[rt][r];
        size_t ob = ((size_t)(b * 256 + mbase + r)) * N + n;
        out[ob] = fmaxf(sout + tout + x[ob], 0.f);
      }
    }
  }
}

extern "C" void kernel_launch(void* const* d_in, const int* in_sizes, int n_in,
                              void* d_out, int out_size, void* d_ws, size_t ws_size,
                              hipStream_t stream)
{
  const float* x   = (const float*)d_in[0];
  const float* Wt1 = (const float*)d_in[1];
  const float* bt1 = (const float*)d_in[2];
  const float* Wt2 = (const float*)d_in[3];
  const float* bt2 = (const float*)d_in[4];
  const float* Wt3 = (const float*)d_in[5];
  const float* bt3 = (const float*)d_in[6];
  const float* Ws1 = (const float*)d_in[7];
  const float* bs1 = (const float*)d_in[8];
  const float* Ws2 = (const float*)d_in[9];
  const float* bs2 = (const float*)d_in[10];
  const float* Ws3 = (const float*)d_in[11];
  const float* bs3 = (const float*)d_in[12];
  float* out = (float*)d_out;

  // workspace: [idx3 384K + spare -> 524288][pool 58.72MB time-sliced]
  // phase1 (knn): xT @0 (33.55M) | xhT @33554432 (16.78M) | idx8 @50331648 (1.05M) | sq4 @51380224 (512K)
  // phase2:       u @0 (16.78M) | t1 @16777216 (8.39M) | t2 @25165824 (8.39M) | s2 @33554432 (25.17M)
  // ordering (CRITICAL for aliasing): k_rerank (last xT/idx8/sq4 reader) BEFORE k_ut1 (writes u/t1 over xT);
  //           k_ut1 (last xhT reader) BEFORE k_te's e1 branch (writes s2 over xhT/idx8/sq4).
  char* ws = (char*)d_ws;
  if (ws_size < 59244544u) return;   // loud, diagnosable failure (output stays poisoned)
  int*   idx3 = (int*)ws;
  char*  P    = ws + 524288;
  float*          xT    = (float*)P;
  unsigned short* xhT   = (unsigned short*)(P + 33554432);
  int*            idx8  = (int*)(P + 50331648);
  float*          sq4   = (float*)(P + 51380224);
  unsigned short* u_ws  = (unsigned short*)P;
  unsigned short* t1_ws = (unsigned short*)(P + 16777216);
  unsigned short* t2_ws = (unsigned short*)(P + 25165824);
  unsigned short* s2_ws = (unsigned short*)(P + 33554432);

  k_cvt   <<<2048, 256, 0, stream>>>(x, xhT, xT, sq4);
  k_pd    <<<1024, 256, 0, stream>>>(xhT, sq4, idx8);
  k_rerank<<<4096, 256, 0, stream>>>(xT, sq4, idx8, idx3);
  k_ut1   <<<768, 256, 0, stream>>>(Ws1, Wt1, bt1, xhT, u_ws, t1_ws);
  k_te    <<<1024, 256, 0, stream>>>(t1_ws, Wt2, bt2, t2_ws, u_ws, idx3, bs1, Ws2, bs2, s2_ws);
  k_e2f   <<<512, 256, 0, stream>>>(s2_ws, t2_ws, Ws3, bs3, Wt3, bt3, x, out);
}

// Round 15
// 251.662 us; speedup vs baseline: 1.0569x; 1.0569x over previous
//
#include <hip/hip_runtime.h>

#define DI __device__ __forceinline__

typedef float f4 __attribute__((ext_vector_type(4)));
typedef float f2 __attribute__((ext_vector_type(2)));
typedef unsigned short u16x8 __attribute__((ext_vector_type(8)));
typedef unsigned short u16x4 __attribute__((ext_vector_type(4)));
typedef __bf16 bf16x8 __attribute__((ext_vector_type(8)));
typedef float f32x4 __attribute__((ext_vector_type(4)));

constexpr int C = 256;
constexpr int N = 2048;
constexpr int BN = 16 * 2048;   // 32768 points total

DI float bf2f(unsigned short h){
  union { unsigned int u; float f; } v; v.u = ((unsigned int)h) << 16; return v.f;
}
DI unsigned short f2bf(float f){
  union { float f; unsigned int u; } v; v.f = f;
  unsigned int r = v.u + 0x7fffu + ((v.u >> 16) & 1u);   // RNE
  return (unsigned short)(r >> 16);
}
DI unsigned int f2u(float f){ union { float f; unsigned int u; } v; v.f = f; return v.u; }
DI float u2f(unsigned int u){ union { unsigned int u; float f; } v; v.u = u; return v.f; }

// top-3 insert, tie -> lower index (matches lax.top_k set semantics)
DI void ins3(float v, int n, float& v0, float& v1, float& v2, int& i0, int& i1, int& i2){
  bool b0 = (v > v0) || (v == v0 && n < i0);
  bool b1 = (v > v1) || (v == v1 && n < i1);
  bool b2 = (v > v2) || (v == v2 && n < i2);
  if (b0){ v2=v1; i2=i1; v1=v0; i1=i0; v0=v; i0=n; }
  else if (b1){ v2=v1; i2=i1; v1=v; i1=n; }
  else if (b2){ v2=v; i2=n; }
}

DI void gload16(const void* g, void* l){
  __builtin_amdgcn_global_load_lds(
      (const __attribute__((address_space(1))) unsigned int*)g,
      (__attribute__((address_space(3))) unsigned int*)l, 16, 0, 0);
}

// ---------- k_cvt: x (B,C,N) fp32 -> xT (BN,256) fp32, xhT (BN,256) bf16, sq4[p][4] partials ----------
__global__ __launch_bounds__(256) void k_cvt(const float* __restrict__ x,
    unsigned short* __restrict__ xhT, float* __restrict__ xT, float* __restrict__ sq4)
{
  __shared__ float T[64][68];
  int bid = blockIdx.x;
  int pt = bid & 31, ct = (bid >> 5) & 3, b = bid >> 7;
  int p0 = pt * 64, c0 = ct * 64;
  int tid = threadIdx.x;
  int cr = tid >> 4, cv = tid & 15;
  const float* xb = x + ((size_t)b * C + c0) * N + p0;
  #pragma unroll
  for (int i = 0; i < 4; i++){
    int c = cr + i * 16;
    f4 v = *(const f4*)(xb + (size_t)c * N + cv * 4);
    T[cv*4+0][c] = v[0]; T[cv*4+1][c] = v[1]; T[cv*4+2][c] = v[2]; T[cv*4+3][c] = v[3];
  }
  __syncthreads();
  int p = tid >> 2, cq = tid & 3;
  size_t rowg = (size_t)b * N + p0 + p;
  float* xtr = xT + rowg * 256 + c0 + cq * 16;
  unsigned short* xhr = xhT + rowg * 256 + c0 + cq * 16;
  float sacc = 0.f;
  #pragma unroll
  for (int j = 0; j < 4; j++){
    f4 v = *(const f4*)&T[p][cq*16 + j*4];
    *(f4*)(xtr + j*4) = v;
    sacc += (v[0]*v[0] + v[1]*v[1]) + (v[2]*v[2] + v[3]*v[3]);
    u16x4 h; h[0]=f2bf(v[0]); h[1]=f2bf(v[1]); h[2]=f2bf(v[2]); h[3]=f2bf(v[3]);
    *(u16x4*)(xhr + j*4) = h;
  }
  sacc += __shfl_xor(sacc, 1, 64);
  sacc += __shfl_xor(sacc, 2, 64);
  if (cq == 0) sq4[rowg * 4 + ct] = sacc;
}

// ---------- k_pd v8b (best known, 67us): A in LDS, per-wave private B triple-buffers, no intra-loop
// barriers, counted per-wave vmcnt; merge scratch padded (193/17 word strides). ----------
__global__ __launch_bounds__(256, 2) void k_pd(const unsigned short* __restrict__ xhT,
    const float* __restrict__ sq4, int* __restrict__ idx8)
{
  __shared__ __align__(16) char sm[81920];
  int wg = blockIdx.x;
  int wid = (wg & 7) * 64 + (wg >> 3);   // XCD chunk swizzle: 2 batches per XCD
  int b = wid >> 5, mt = wid & 31;
  int m0 = mt * 64;
  int tid = threadIdx.x, w = tid >> 6, l = tid & 63;
  const unsigned short* xb = xhT + (size_t)b * N * 256;
  const float* sqb4 = sq4 + (size_t)b * N * 4;
  char* Ab = sm + 49152;          // A tile base
  char* wbuf = sm + w * 12288;    // this wave's 3 B buffers

  // stage A cooperatively (coalesced source, swizzled rows)
  #pragma unroll
  for (int i = 0; i < 8; i++){
    int flat = i * 256 + tid;
    int m = flat >> 5, c = flat & 31;
    gload16(xb + (size_t)(m0 + m) * 256 + ((c ^ (m & 7)) << 3), Ab + flat * 16);
  }
  // per-wave B prefetch: tiles 0 and 1
  #pragma unroll
  for (int t = 0; t < 2; t++){
    #pragma unroll
    for (int i = 0; i < 4; i++){
      int p = i * 4 + (l >> 4), c = l & 15;
      gload16(xb + (size_t)(w * 16 + p) * 256 + t * 128 + ((c ^ (p & 7)) << 3),
              wbuf + t * 4096 + (i * 64 + l) * 16);
    }
  }
  asm volatile("s_waitcnt vmcnt(8)" ::: "memory");   // A complete; B0/B1 in flight
  __builtin_amdgcn_s_barrier();

  bf16x8 af[4][8];
  #pragma unroll
  for (int rt = 0; rt < 4; rt++)
    #pragma unroll
    for (int ks = 0; ks < 8; ks++){
      int m = rt * 16 + (l & 15);
      int ch = ks * 4 + (l >> 4);
      af[rt][ks] = *(const bf16x8*)(Ab + m * 512 + ((ch ^ (m & 7)) << 4));
    }

  float K[16][3];
  #pragma unroll
  for (int a = 0; a < 16; a++){ K[a][0] = 0.f; K[a][1] = 0.f; K[a][2] = 0.f; }

  f32x4 acc[4];
  for (int it = 0; it < 64; it++){
    if (it < 62){
      int nx = it + 2;
      int P0 = (nx >> 1) * 64, kh2 = nx & 1;
      char* dst = wbuf + (nx % 3) * 4096;
      #pragma unroll
      for (int i = 0; i < 4; i++){
        int p = i * 4 + (l >> 4), c = l & 15;
        gload16(xb + (size_t)(P0 + w * 16 + p) * 256 + kh2 * 128 + ((c ^ (p & 7)) << 3),
                dst + (i * 64 + l) * 16);
      }
    }
    if (it < 62)       asm volatile("s_waitcnt vmcnt(8)" ::: "memory");
    else if (it == 62) asm volatile("s_waitcnt vmcnt(4)" ::: "memory");
    else               asm volatile("s_waitcnt vmcnt(0)" ::: "memory");

    const char* bb = wbuf + (it % 3) * 4096;
    int kh = it & 1;
    if (kh == 0){
      f32x4 z = {0.f, 0.f, 0.f, 0.f};
      #pragma unroll
      for (int rt = 0; rt < 4; rt++) acc[rt] = z;
    }
    #pragma unroll
    for (int ks = 0; ks < 4; ks++){
      int p = l & 15;
      int ch = ks * 4 + (l >> 4);
      bf16x8 bv = *(const bf16x8*)(bb + p * 256 + ((ch ^ (p & 7)) << 4));
      if (kh == 0){
        #pragma unroll
        for (int rt = 0; rt < 4; rt++)
          acc[rt] = __builtin_amdgcn_mfma_f32_16x16x32_bf16(af[rt][ks], bv, acc[rt], 0, 0, 0);
      } else {
        #pragma unroll
        for (int rt = 0; rt < 4; rt++)
          acc[rt] = __builtin_amdgcn_mfma_f32_16x16x32_bf16(af[rt][4 + ks], bv, acc[rt], 0, 0, 0);
      }
    }
    if (kh == 1){
      int col = (it >> 1) * 64 + w * 16 + (l & 15);
      f4 s4 = *(const f4*)(sqb4 + (size_t)col * 4);
      float nb = 1024.f - ((s4[0] + s4[1]) + (s4[2] + s4[3]));
      unsigned int ib = (unsigned int)(2047 - col);
      #pragma unroll
      for (int rt = 0; rt < 4; rt++)
        #pragma unroll
        for (int r = 0; r < 4; r++){
          float v = fmaf(acc[rt][r], 2.f, nb);
          float key = u2f((f2u(v) & 0xFFFFF800u) | ib);
          int a = rt * 4 + r;
          K[a][2] = __builtin_amdgcn_fmed3f(K[a][1], K[a][2], key);
          K[a][1] = __builtin_amdgcn_fmed3f(K[a][0], K[a][1], key);
          K[a][0] = fmaxf(K[a][0], key);
        }
    }
  }
  __syncthreads();   // all waves done with B buffers & A reads; overlay merge scratch
  // merge: 64 rows x 192 keys, stride 193 words (193 % 32 = 1 -> 2-way banks on reads)
  float* mK = (float*)sm;
  #pragma unroll
  for (int rt = 0; rt < 4; rt++)
    #pragma unroll
    for (int r = 0; r < 4; r++){
      int row = rt * 16 + (l >> 4) * 4 + r;
      int base = row * 193 + w * 48 + (l & 15) * 3;
      mK[base+0] = K[rt*4+r][0]; mK[base+1] = K[rt*4+r][1]; mK[base+2] = K[rt*4+r][2];
    }
  __syncthreads();
  float* aux = (float*)(sm + 49408);   // after 64*193*4 B; stride 17 words
  {
    int row = tid >> 2, q = tid & 3;
    float t0 = 0.f, t1 = 0.f, t2 = 0.f, t3 = 0.f;
    const float* src = mK + row * 193 + q * 48;
    for (int s = 0; s < 48; s++){
      float v = src[s];
      t3 = __builtin_amdgcn_fmed3f(t2, t3, v);
      t2 = __builtin_amdgcn_fmed3f(t1, t2, v);
      t1 = __builtin_amdgcn_fmed3f(t0, t1, v);
      t0 = fmaxf(t0, v);
    }
    float* d = aux + row * 17 + q * 4;
    d[0] = t0; d[1] = t1; d[2] = t2; d[3] = t3;
  }
  __syncthreads();
  if (tid < 64){
    float u0=0.f,u1=0.f,u2=0.f,u3=0.f,u4=0.f,u5=0.f,u6=0.f,u7=0.f;
    const float* srcp = aux + tid * 17;
    #pragma unroll
    for (int s = 0; s < 16; s++){
      float v = srcp[s];
      u7 = __builtin_amdgcn_fmed3f(u6, u7, v);
      u6 = __builtin_amdgcn_fmed3f(u5, u6, v);
      u5 = __builtin_amdgcn_fmed3f(u4, u5, v);
      u4 = __builtin_amdgcn_fmed3f(u3, u4, v);
      u3 = __builtin_amdgcn_fmed3f(u2, u3, v);
      u2 = __builtin_amdgcn_fmed3f(u1, u2, v);
      u1 = __builtin_amdgcn_fmed3f(u0, u1, v);
      u0 = fmaxf(u0, v);
    }
    int* d = idx8 + ((size_t)(b * N + m0 + tid)) * 8;
    d[0]=2047-(int)(f2u(u0)&2047u); d[1]=2047-(int)(f2u(u1)&2047u);
    d[2]=2047-(int)(f2u(u2)&2047u); d[3]=2047-(int)(f2u(u3)&2047u);
    d[4]=2047-(int)(f2u(u4)&2047u); d[5]=2047-(int)(f2u(u5)&2047u);
    d[6]=2047-(int)(f2u(u6)&2047u); d[7]=2047-(int)(f2u(u7)&2047u);
  }
}

// ---------- k_rerank: exact fp32 pd over 8 candidates, pair-parallel (2 rows/wave) ----------
__global__ __launch_bounds__(256) void k_rerank(const float* __restrict__ xT,
    const float* __restrict__ sq4, const int* __restrict__ idx8, int* __restrict__ idx3)
{
  int w = threadIdx.x >> 6, l = threadIdx.x & 63;
  int h = l >> 5, lh = l & 31;
  int wv = blockIdx.x * 4 + w;
  #pragma unroll
  for (int rr = 0; rr < 2; rr++){
    int row = wv * 2 + rr;
    int b = row >> 11;
    const float* xm = xT + (size_t)row * 256 + lh * 8;
    f4 xm0 = *(const f4*)xm;
    f4 xm1 = *(const f4*)(xm + 4);
    const int* cb = idx8 + (size_t)row * 8;
    int nn[8];
    #pragma unroll
    for (int c2 = 0; c2 < 8; c2++) nn[c2] = cb[c2];
    f4 a0[4], a1[4];
    #pragma unroll
    for (int j = 0; j < 4; j++){
      int n = nn[2*j + h];
      const float* xn = xT + ((size_t)(b * N + n)) * 256 + lh * 8;
      a0[j] = *(const f4*)xn;
      a1[j] = *(const f4*)(xn + 4);
    }
    float v0=-3e38f, v1=v0, v2=v0; int i0=0x7fffffff, i1=i0, i2=i0;
    #pragma unroll
    for (int j = 0; j < 4; j++){
      float s = ((xm0[0]*a0[j][0] + xm0[1]*a0[j][1]) + (xm0[2]*a0[j][2] + xm0[3]*a0[j][3]))
              + ((xm1[0]*a1[j][0] + xm1[1]*a1[j][1]) + (xm1[2]*a1[j][2] + xm1[3]*a1[j][3]));
      #pragma unroll
      for (int d = 1; d < 32; d <<= 1) s += __shfl_xor(s, d, 64);
      float so = __shfl_xor(s, 32, 64);
      float pe = h ? so : s;
      float po = h ? s : so;
      int ne = nn[2*j], no = nn[2*j+1];
      f4 s4e = *(const f4*)(sq4 + ((size_t)(b * N + ne)) * 4);
      f4 s4o = *(const f4*)(sq4 + ((size_t)(b * N + no)) * 4);
      float ve = 2.f * pe - ((s4e[0] + s4e[1]) + (s4e[2] + s4e[3]));
      float vo = 2.f * po - ((s4o[0] + s4o[1]) + (s4o[2] + s4o[3]));
      ins3(ve, ne, v0, v1, v2, i0, i1, i2);
      ins3(vo, no, v0, v1, v2, i0, i1, i2);
    }
    if (l == 0){
      size_t ob = (size_t)row * 3;
      idx3[ob] = i0; idx3[ob+1] = i1; idx3[ob+2] = i2;
    }
  }
}

// ---------- k_ut1 (MFMA): rows 0..255 -> u (Ws1 halves), 256..383 -> t1=relu(Wt1 x + bt1) ----------
__global__ __launch_bounds__(256, 2) void k_ut1(const float* __restrict__ Ws1,
    const float* __restrict__ Wt1, const float* __restrict__ bt1,
    const unsigned short* __restrict__ xhT,
    unsigned short* __restrict__ u_ws, unsigned short* __restrict__ t1_ws)
{
  __shared__ __align__(16) unsigned short A[64 * 256];
  int wg = blockIdx.x;
  int wid = (wg & 7) * 96 + (wg >> 3);
  int mb = wid % 6, pt = wid / 6;
  int m0 = mb * 64, p0 = pt * 256;
  int tid = threadIdx.x, w = tid >> 6, l = tid & 63;
  #pragma unroll
  for (int i = 0; i < 8; i++){
    int flat = i * 256 + tid;
    int m = flat >> 5, c = flat & 31;
    int mg = m0 + m;
    const float* srcp;
    if (mg < 128)      srcp = Ws1 + (size_t)mg * 512 + c * 8;
    else if (mg < 256) srcp = Ws1 + (size_t)(mg - 128) * 512 + 256 + c * 8;
    else               srcp = Wt1 + (size_t)(mg - 256) * 256 + c * 8;
    f4 v0 = *(const f4*)srcp, v1 = *(const f4*)(srcp + 4);
    u16x8 h;
    h[0]=f2bf(v0[0]); h[1]=f2bf(v0[1]); h[2]=f2bf(v0[2]); h[3]=f2bf(v0[3]);
    h[4]=f2bf(v1[0]); h[5]=f2bf(v1[1]); h[6]=f2bf(v1[2]); h[7]=f2bf(v1[3]);
    *(u16x8*)(A + m * 256 + ((c ^ (m & 7)) << 3)) = h;
  }
  __syncthreads();
  bf16x8 af[4][8];
  #pragma unroll
  for (int rt = 0; rt < 4; rt++)
    #pragma unroll
    for (int ks = 0; ks < 8; ks++){
      int m = rt * 16 + (l & 15);
      int ch = ks * 4 + (l >> 4);
      af[rt][ks] = *(const bf16x8*)((const char*)A + m * 512 + ((ch ^ (m & 7)) << 4));
    }
  bool isU = (m0 < 256);
  f4 bias[4];
  if (!isU){
    #pragma unroll
    for (int rt = 0; rt < 4; rt++)
      bias[rt] = *(const f4*)(bt1 + (m0 - 256) + rt * 16 + (l >> 4) * 4);
  }
  for (int ct = 0; ct < 4; ct++){
    int p = p0 + ct * 64 + w * 16 + (l & 15);
    const unsigned short* bp = xhT + (size_t)p * 256 + (l >> 4) * 8;
    f32x4 acc[4];
    f32x4 z = {0.f, 0.f, 0.f, 0.f};
    #pragma unroll
    for (int rt = 0; rt < 4; rt++) acc[rt] = z;
    #pragma unroll
    for (int ks = 0; ks < 8; ks++){
      bf16x8 bv = *(const bf16x8*)(bp + ks * 32);
      #pragma unroll
      for (int rt = 0; rt < 4; rt++)
        acc[rt] = __builtin_amdgcn_mfma_f32_16x16x32_bf16(af[rt][ks], bv, acc[rt], 0, 0, 0);
    }
    if (isU){
      #pragma unroll
      for (int rt = 0; rt < 4; rt++){
        u16x4 h;
        h[0]=f2bf(acc[rt][0]); h[1]=f2bf(acc[rt][1]); h[2]=f2bf(acc[rt][2]); h[3]=f2bf(acc[rt][3]);
        *(u16x4*)(u_ws + (size_t)p * 256 + m0 + rt * 16 + (l >> 4) * 4) = h;
      }
    } else {
      #pragma unroll
      for (int rt = 0; rt < 4; rt++){
        u16x4 h;
        h[0]=f2bf(fmaxf(acc[rt][0] + bias[rt][0], 0.f));
        h[1]=f2bf(fmaxf(acc[rt][1] + bias[rt][1], 0.f));
        h[2]=f2bf(fmaxf(acc[rt][2] + bias[rt][2], 0.f));
        h[3]=f2bf(fmaxf(acc[rt][3] + bias[rt][3], 0.f));
        *(u16x4*)(t1_ws + (size_t)p * 128 + (m0 - 256) + rt * 16 + (l >> 4) * 4) = h;
      }
    }
  }
}

// ---------- k_te (fused independent): blocks 0..511 = t2 grouped conv; 512..1023 = e1 gather+s1+s2 ----------
__global__ __launch_bounds__(256) void k_te(const unsigned short* __restrict__ t1_ws,
    const float* __restrict__ Wt2, const float* __restrict__ bt2,
    unsigned short* __restrict__ t2_ws,
    const unsigned short* __restrict__ u_ws, const int* __restrict__ idx_ws,
    const float* __restrict__ bs1, const float* __restrict__ Ws2,
    const float* __restrict__ bs2, unsigned short* __restrict__ s2_ws)
{
  __shared__ float w2[1536];
  __shared__ float b2[128];
  __shared__ float sb1[128], sb2[128], sw2[512];
  int tid = threadIdx.x;
  if (blockIdx.x < 512){
    for (int i = tid; i < 1536; i += 256) w2[i] = Wt2[i];
    if (tid < 128) b2[tid] = bt2[tid];
    __syncthreads();
    int p = blockIdx.x * 64 + (tid >> 2);
    int q = tid & 3;
    int n = p & (N - 1);
    const unsigned short* rp = t1_ws + (size_t)p * 128;
    u16x8 zz = {0,0,0,0,0,0,0,0};
    #pragma unroll
    for (int g8 = 0; g8 < 4; g8++){
      int ch0 = q*32 + g8*8;
      u16x8 vm1 = (n > 0)     ? *(const u16x8*)(rp - 128 + ch0) : zz;
      u16x8 v0  =               *(const u16x8*)(rp + ch0);
      u16x8 vp1 = (n < N - 1) ? *(const u16x8*)(rp + 128 + ch0) : zz;
      float fm1[8], f0[8], fp1[8];
      #pragma unroll
      for (int e = 0; e < 8; e++){ fm1[e]=bf2f(vm1[e]); f0[e]=bf2f(v0[e]); fp1[e]=bf2f(vp1[e]); }
      u16x8 o;
      #pragma unroll
      for (int j = 0; j < 8; j++){
        int wch = ch0 + j, gb = j & ~3;
        float acc = b2[wch];
        #pragma unroll
        for (int i = 0; i < 4; i++){
          acc += w2[wch*12 + i*3 + 0] * fm1[gb + i];
          acc += w2[wch*12 + i*3 + 1] * f0[gb + i];
          acc += w2[wch*12 + i*3 + 2] * fp1[gb + i];
        }
        o[j] = f2bf(fmaxf(acc, 0.f));
      }
      *(u16x8*)(t2_ws + (size_t)p * 128 + ch0) = o;
    }
  } else {
    if (tid < 128){ sb1[tid] = bs1[tid]; sb2[tid] = bs2[tid]; }
    sw2[tid] = Ws2[tid]; sw2[tid+256] = Ws2[tid+256];
    __syncthreads();
    int p0 = (blockIdx.x - 512) * 64;
    #pragma unroll
    for (int rep = 0; rep < 3; rep++){
      int task = rep*256 + tid;
      int r = task >> 2, q = task & 3;
      int pl = r / 3, k = r - pl*3;
      int p = p0 + pl;
      int b = p >> 11;
      int m = idx_ws[(size_t)p*3 + k] & (N - 1);
      const unsigned short* ua = u_ws + ((size_t)(b*N + m))*256 + q*32;
      const unsigned short* ub = u_ws + ((size_t)p)*256 + 128 + q*32;
      float s1v[32];
      #pragma unroll
      for (int jj = 0; jj < 4; jj++){
        u16x8 a  = *(const u16x8*)(ua + jj*8);
        u16x8 cbv = *(const u16x8*)(ub + jj*8);
        #pragma unroll
        for (int e = 0; e < 8; e++){
          int j = jj*8 + e;
          s1v[j] = fmaxf(bf2f(a[e]) + bf2f(cbv[e]) + sb1[q*32 + j], 0.f);
        }
      }
      #pragma unroll
      for (int jj = 0; jj < 4; jj++){
        u16x8 o;
        #pragma unroll
        for (int e = 0; e < 8; e++){
          int j = jj*8 + e;
          int ch = q*32 + j, gb = j & ~3;
          float a2 = sb2[ch] + sw2[ch*4+0]*s1v[gb]   + sw2[ch*4+1]*s1v[gb+1]
                             + sw2[ch*4+2]*s1v[gb+2] + sw2[ch*4+3]*s1v[gb+3];
          o[e] = f2bf(fmaxf(a2, 0.f));
        }
        *(u16x8*)(s2_ws + ((size_t)k * BN + p) * 128 + q*32 + jj*8) = o;
      }
    }
  }
}

// ---------- k_e2f (fused): s3_k = Ws3.s2_k, tout = Wt3.t2 ; out = relu(max_k(s3)+bs3 + tout+bt3 + x) ----------
__global__ __launch_bounds__(256, 2) void k_e2f(const unsigned short* __restrict__ s2_ws,
    const unsigned short* __restrict__ t2_ws,
    const float* __restrict__ Ws3, const float* __restrict__ bs3,
    const float* __restrict__ Wt3, const float* __restrict__ bt3,
    const float* __restrict__ x, float* __restrict__ out)
{
  __shared__ __align__(16) unsigned short As[64 * 128];
  __shared__ __align__(16) unsigned short At[64 * 128];
  int wg = blockIdx.x;
  int wid = (wg & 7) * 64 + (wg >> 3);
  int mb = wid & 3, pt = wid >> 2;
  int m0 = mb * 64, p0 = pt * 256;
  int tid = threadIdx.x, w = tid >> 6, l = tid & 63;
  #pragma unroll
  for (int i = 0; i < 4; i++){
    int flat = i * 256 + tid;
    int m = flat >> 4, c = flat & 15;
    {
      const float* srcp = Ws3 + (size_t)(m0 + m) * 128 + c * 8;
      f4 v0 = *(const f4*)srcp, v1 = *(const f4*)(srcp + 4);
      u16x8 h;
      h[0]=f2bf(v0[0]); h[1]=f2bf(v0[1]); h[2]=f2bf(v0[2]); h[3]=f2bf(v0[3]);
      h[4]=f2bf(v1[0]); h[5]=f2bf(v1[1]); h[6]=f2bf(v1[2]); h[7]=f2bf(v1[3]);
      *(u16x8*)(As + m * 128 + ((c ^ (m & 7)) << 3)) = h;
    }
    {
      const float* srcp = Wt3 + (size_t)(m0 + m) * 128 + c * 8;
      f4 v0 = *(const f4*)srcp, v1 = *(const f4*)(srcp + 4);
      u16x8 h;
      h[0]=f2bf(v0[0]); h[1]=f2bf(v0[1]); h[2]=f2bf(v0[2]); h[3]=f2bf(v0[3]);
      h[4]=f2bf(v1[0]); h[5]=f2bf(v1[1]); h[6]=f2bf(v1[2]); h[7]=f2bf(v1[3]);
      *(u16x8*)(At + m * 128 + ((c ^ (m & 7)) << 3)) = h;
    }
  }
  __syncthreads();
  bf16x8 afs[4][4], aft[4][4];
  #pragma unroll
  for (int rt = 0; rt < 4; rt++)
    #pragma unroll
    for (int ks = 0; ks < 4; ks++){
      int m = rt * 16 + (l & 15);
      int ch = ks * 4 + (l >> 4);
      afs[rt][ks] = *(const bf16x8*)((const char*)As + m * 256 + ((ch ^ (m & 7)) << 4));
      aft[rt][ks] = *(const bf16x8*)((const char*)At + m * 256 + ((ch ^ (m & 7)) << 4));
    }
  f4 biasS[4], biasT[4];
  #pragma unroll
  for (int rt = 0; rt < 4; rt++){
    biasS[rt] = *(const f4*)(bs3 + m0 + rt * 16 + (l >> 4) * 4);
    biasT[rt] = *(const f4*)(bt3 + m0 + rt * 16 + (l >> 4) * 4);
  }
  for (int ct = 0; ct < 4; ct++){
    int p = p0 + ct * 64 + w * 16 + (l & 15);
    int b = p >> 11, n = p & (N - 1);
    const unsigned short* bp0 = s2_ws + ((size_t)(0 * BN + p)) * 128 + (l >> 4) * 8;
    const unsigned short* bp1 = s2_ws + ((size_t)(1 * BN + p)) * 128 + (l >> 4) * 8;
    const unsigned short* bp2 = s2_ws + ((size_t)(2 * BN + p)) * 128 + (l >> 4) * 8;
    const unsigned short* bpt = t2_ws + ((size_t)p) * 128 + (l >> 4) * 8;
    f32x4 acc[4][4];
    f32x4 z = {0.f, 0.f, 0.f, 0.f};
    #pragma unroll
    for (int rt = 0; rt < 4; rt++){ acc[rt][0]=z; acc[rt][1]=z; acc[rt][2]=z; acc[rt][3]=z; }
    #pragma unroll
    for (int ks = 0; ks < 4; ks++){
      bf16x8 bv0 = *(const bf16x8*)(bp0 + ks * 32);
      bf16x8 bv1 = *(const bf16x8*)(bp1 + ks * 32);
      bf16x8 bv2 = *(const bf16x8*)(bp2 + ks * 32);
      bf16x8 bvt = *(const bf16x8*)(bpt + ks * 32);
      #pragma unroll
      for (int rt = 0; rt < 4; rt++){
        acc[rt][0] = __builtin_amdgcn_mfma_f32_16x16x32_bf16(afs[rt][ks], bv0, acc[rt][0], 0, 0, 0);
        acc[rt][1] = __builtin_amdgcn_mfma_f32_16x16x32_bf16(afs[rt][ks], bv1, acc[rt][1], 0, 0, 0);
        acc[rt][2] = __builtin_amdgcn_mfma_f32_16x16x32_bf16(afs[rt][ks], bv2, acc[rt][2], 0, 0, 0);
        acc[rt][3] = __builtin_amdgcn_mfma_f32_16x16x32_bf16(aft[rt][ks], bvt, acc[rt][3], 0, 0, 0);
      }
    }
    #pragma unroll
    for (int rt = 0; rt < 4; rt++){
      int mbase = m0 + rt * 16 + (l >> 4) * 4;
      #pragma unroll
      for (int r = 0; r < 4; r++){
        float sout = fmaxf(fmaxf(acc[rt][0][r], acc[rt][1][r]), acc[rt][2][r]) + biasS[rt][r];
        float tout = acc[rt][3][r] + biasT[rt][r];
        size_t ob = ((size_t)(b * 256 + mbase + r)) * N + n;
        out[ob] = fmaxf(sout + tout + x[ob], 0.f);
      }
    }
  }
}

extern "C" void kernel_launch(void* const* d_in, const int* in_sizes, int n_in,
                              void* d_out, int out_size, void* d_ws, size_t ws_size,
                              hipStream_t stream)
{
  const float* x   = (const float*)d_in[0];
  const float* Wt1 = (const float*)d_in[1];
  const float* bt1 = (const float*)d_in[2];
  const float* Wt2 = (const float*)d_in[3];
  const float* bt2 = (const float*)d_in[4];
  const float* Wt3 = (const float*)d_in[5];
  const float* bt3 = (const float*)d_in[6];
  const float* Ws1 = (const float*)d_in[7];
  const float* bs1 = (const float*)d_in[8];
  const float* Ws2 = (const float*)d_in[9];
  const float* bs2 = (const float*)d_in[10];
  const float* Ws3 = (const float*)d_in[11];
  const float* bs3 = (const float*)d_in[12];
  float* out = (float*)d_out;

  // workspace: [idx3 384K + spare -> 524288][pool 58.72MB time-sliced]
  // phase1 (knn): xT @0 (33.55M) | xhT @33554432 (16.78M) | idx8 @50331648 (1.05M) | sq4 @51380224 (512K)
  // phase2:       u @0 (16.78M) | t1 @16777216 (8.39M) | t2 @25165824 (8.39M) | s2 @33554432 (25.17M)
  // ordering (CRITICAL for aliasing): k_rerank (last xT/idx8/sq4 reader) BEFORE k_ut1 (writes u/t1 over xT);
  //           k_ut1 (last xhT reader) BEFORE k_te's e1 branch (writes s2 over xhT/idx8/sq4).
  char* ws = (char*)d_ws;
  if (ws_size < 59244544u) return;   // loud, diagnosable failure (output stays poisoned)
  int*   idx3 = (int*)ws;
  char*  P    = ws + 524288;
  float*          xT    = (float*)P;
  unsigned short* xhT   = (unsigned short*)(P + 33554432);
  int*            idx8  = (int*)(P + 50331648);
  float*          sq4   = (float*)(P + 51380224);
  unsigned short* u_ws  = (unsigned short*)P;
  unsigned short* t1_ws = (unsigned short*)(P + 16777216);
  unsigned short* t2_ws = (unsigned short*)(P + 25165824);
  unsigned short* s2_ws = (unsigned short*)(P + 33554432);

  k_cvt   <<<2048, 256, 0, stream>>>(x, xhT, xT, sq4);
  k_pd    <<<512, 256, 0, stream>>>(xhT, sq4, idx8);
  k_rerank<<<4096, 256, 0, stream>>>(xT, sq4, idx8, idx3);
  k_ut1   <<<768, 256, 0, stream>>>(Ws1, Wt1, bt1, xhT, u_ws, t1_ws);
  k_te    <<<1024, 256, 0, stream>>>(t1_ws, Wt2, bt2, t2_ws, u_ws, idx3, bs1, Ws2, bs2, s2_ws);
  k_e2f   <<<512, 256, 0, stream>>>(s2_ws, t2_ws, Ws3, bs3, Wt3, bt3, x, out);
}

// Round 16
// 231.761 us; speedup vs baseline: 1.1477x; 1.0859x over previous
//
#include <hip/hip_runtime.h>

#define DI __device__ __forceinline__

typedef float f4 __attribute__((ext_vector_type(4)));
typedef float f2 __attribute__((ext_vector_type(2)));
typedef unsigned short u16x8 __attribute__((ext_vector_type(8)));
typedef unsigned short u16x4 __attribute__((ext_vector_type(4)));
typedef __bf16 bf16x8 __attribute__((ext_vector_type(8)));
typedef float f32x4 __attribute__((ext_vector_type(4)));

constexpr int C = 256;
constexpr int N = 2048;
constexpr int BN = 16 * 2048;   // 32768 points total

DI float bf2f(unsigned short h){
  union { unsigned int u; float f; } v; v.u = ((unsigned int)h) << 16; return v.f;
}
DI unsigned short f2bf(float f){
  union { float f; unsigned int u; } v; v.f = f;
  unsigned int r = v.u + 0x7fffu + ((v.u >> 16) & 1u);   // RNE
  return (unsigned short)(r >> 16);
}
DI unsigned int f2u(float f){ union { float f; unsigned int u; } v; v.f = f; return v.u; }
DI float u2f(unsigned int u){ union { unsigned int u; float f; } v; v.u = u; return v.f; }

// top-3 insert, tie -> lower index (matches lax.top_k set semantics)
DI void ins3(float v, int n, float& v0, float& v1, float& v2, int& i0, int& i1, int& i2){
  bool b0 = (v > v0) || (v == v0 && n < i0);
  bool b1 = (v > v1) || (v == v1 && n < i1);
  bool b2 = (v > v2) || (v == v2 && n < i2);
  if (b0){ v2=v1; i2=i1; v1=v0; i1=i0; v0=v; i0=n; }
  else if (b1){ v2=v1; i2=i1; v1=v; i1=n; }
  else if (b2){ v2=v; i2=n; }
}

DI void gload16(const void* g, void* l){
  __builtin_amdgcn_global_load_lds(
      (const __attribute__((address_space(1))) unsigned int*)g,
      (__attribute__((address_space(3))) unsigned int*)l, 16, 0, 0);
}

// ---------- k_cvt: x (B,C,N) fp32 -> xT (BN,256) fp32, xhT (BN,256) bf16, sq4[p][4] partials ----------
__global__ __launch_bounds__(256) void k_cvt(const float* __restrict__ x,
    unsigned short* __restrict__ xhT, float* __restrict__ xT, float* __restrict__ sq4)
{
  __shared__ float T[64][68];
  int bid = blockIdx.x;
  int pt = bid & 31, ct = (bid >> 5) & 3, b = bid >> 7;
  int p0 = pt * 64, c0 = ct * 64;
  int tid = threadIdx.x;
  int cr = tid >> 4, cv = tid & 15;
  const float* xb = x + ((size_t)b * C + c0) * N + p0;
  #pragma unroll
  for (int i = 0; i < 4; i++){
    int c = cr + i * 16;
    f4 v = *(const f4*)(xb + (size_t)c * N + cv * 4);
    T[cv*4+0][c] = v[0]; T[cv*4+1][c] = v[1]; T[cv*4+2][c] = v[2]; T[cv*4+3][c] = v[3];
  }
  __syncthreads();
  int p = tid >> 2, cq = tid & 3;
  size_t rowg = (size_t)b * N + p0 + p;
  float* xtr = xT + rowg * 256 + c0 + cq * 16;
  unsigned short* xhr = xhT + rowg * 256 + c0 + cq * 16;
  float sacc = 0.f;
  #pragma unroll
  for (int j = 0; j < 4; j++){
    f4 v = *(const f4*)&T[p][cq*16 + j*4];
    *(f4*)(xtr + j*4) = v;
    sacc += (v[0]*v[0] + v[1]*v[1]) + (v[2]*v[2] + v[3]*v[3]);
    u16x4 h; h[0]=f2bf(v[0]); h[1]=f2bf(v[1]); h[2]=f2bf(v[2]); h[3]=f2bf(v[3]);
    *(u16x4*)(xhr + j*4) = h;
  }
  sacc += __shfl_xor(sacc, 1, 64);
  sacc += __shfl_xor(sacc, 2, 64);
  if (cq == 0) sq4[rowg * 4 + ct] = sacc;
}

// ---------- k_pd v8b (best known, 67us): A in LDS, per-wave private B triple-buffers, no intra-loop
// barriers, counted per-wave vmcnt; merge scratch padded (193/17 word strides). ----------
__global__ __launch_bounds__(256, 2) void k_pd(const unsigned short* __restrict__ xhT,
    const float* __restrict__ sq4, int* __restrict__ idx8)
{
  __shared__ __align__(16) char sm[81920];
  int wg = blockIdx.x;
  int wid = (wg & 7) * 64 + (wg >> 3);   // XCD chunk swizzle: 2 batches per XCD
  int b = wid >> 5, mt = wid & 31;
  int m0 = mt * 64;
  int tid = threadIdx.x, w = tid >> 6, l = tid & 63;
  const unsigned short* xb = xhT + (size_t)b * N * 256;
  const float* sqb4 = sq4 + (size_t)b * N * 4;
  char* Ab = sm + 49152;          // A tile base
  char* wbuf = sm + w * 12288;    // this wave's 3 B buffers

  // stage A cooperatively (coalesced source, swizzled rows)
  #pragma unroll
  for (int i = 0; i < 8; i++){
    int flat = i * 256 + tid;
    int m = flat >> 5, c = flat & 31;
    gload16(xb + (size_t)(m0 + m) * 256 + ((c ^ (m & 7)) << 3), Ab + flat * 16);
  }
  // per-wave B prefetch: tiles 0 and 1
  #pragma unroll
  for (int t = 0; t < 2; t++){
    #pragma unroll
    for (int i = 0; i < 4; i++){
      int p = i * 4 + (l >> 4), c = l & 15;
      gload16(xb + (size_t)(w * 16 + p) * 256 + t * 128 + ((c ^ (p & 7)) << 3),
              wbuf + t * 4096 + (i * 64 + l) * 16);
    }
  }
  asm volatile("s_waitcnt vmcnt(8)" ::: "memory");   // A complete; B0/B1 in flight
  __builtin_amdgcn_s_barrier();

  bf16x8 af[4][8];
  #pragma unroll
  for (int rt = 0; rt < 4; rt++)
    #pragma unroll
    for (int ks = 0; ks < 8; ks++){
      int m = rt * 16 + (l & 15);
      int ch = ks * 4 + (l >> 4);
      af[rt][ks] = *(const bf16x8*)(Ab + m * 512 + ((ch ^ (m & 7)) << 4));
    }

  float K[16][3];
  #pragma unroll
  for (int a = 0; a < 16; a++){ K[a][0] = 0.f; K[a][1] = 0.f; K[a][2] = 0.f; }

  f32x4 acc[4];
  for (int it = 0; it < 64; it++){
    if (it < 62){
      int nx = it + 2;
      int P0 = (nx >> 1) * 64, kh2 = nx & 1;
      char* dst = wbuf + (nx % 3) * 4096;
      #pragma unroll
      for (int i = 0; i < 4; i++){
        int p = i * 4 + (l >> 4), c = l & 15;
        gload16(xb + (size_t)(P0 + w * 16 + p) * 256 + kh2 * 128 + ((c ^ (p & 7)) << 3),
                dst + (i * 64 + l) * 16);
      }
    }
    if (it < 62)       asm volatile("s_waitcnt vmcnt(8)" ::: "memory");
    else if (it == 62) asm volatile("s_waitcnt vmcnt(4)" ::: "memory");
    else               asm volatile("s_waitcnt vmcnt(0)" ::: "memory");

    const char* bb = wbuf + (it % 3) * 4096;
    int kh = it & 1;
    if (kh == 0){
      f32x4 z = {0.f, 0.f, 0.f, 0.f};
      #pragma unroll
      for (int rt = 0; rt < 4; rt++) acc[rt] = z;
    }
    #pragma unroll
    for (int ks = 0; ks < 4; ks++){
      int p = l & 15;
      int ch = ks * 4 + (l >> 4);
      bf16x8 bv = *(const bf16x8*)(bb + p * 256 + ((ch ^ (p & 7)) << 4));
      if (kh == 0){
        #pragma unroll
        for (int rt = 0; rt < 4; rt++)
          acc[rt] = __builtin_amdgcn_mfma_f32_16x16x32_bf16(af[rt][ks], bv, acc[rt], 0, 0, 0);
      } else {
        #pragma unroll
        for (int rt = 0; rt < 4; rt++)
          acc[rt] = __builtin_amdgcn_mfma_f32_16x16x32_bf16(af[rt][4 + ks], bv, acc[rt], 0, 0, 0);
      }
    }
    if (kh == 1){
      int col = (it >> 1) * 64 + w * 16 + (l & 15);
      f4 s4 = *(const f4*)(sqb4 + (size_t)col * 4);
      float nb = 1024.f - ((s4[0] + s4[1]) + (s4[2] + s4[3]));
      unsigned int ib = (unsigned int)(2047 - col);
      #pragma unroll
      for (int rt = 0; rt < 4; rt++)
        #pragma unroll
        for (int r = 0; r < 4; r++){
          float v = fmaf(acc[rt][r], 2.f, nb);
          float key = u2f((f2u(v) & 0xFFFFF800u) | ib);
          int a = rt * 4 + r;
          K[a][2] = __builtin_amdgcn_fmed3f(K[a][1], K[a][2], key);
          K[a][1] = __builtin_amdgcn_fmed3f(K[a][0], K[a][1], key);
          K[a][0] = fmaxf(K[a][0], key);
        }
    }
  }
  __syncthreads();   // all waves done with B buffers & A reads; overlay merge scratch
  // merge: 64 rows x 192 keys, stride 193 words (193 % 32 = 1 -> 2-way banks on reads)
  float* mK = (float*)sm;
  #pragma unroll
  for (int rt = 0; rt < 4; rt++)
    #pragma unroll
    for (int r = 0; r < 4; r++){
      int row = rt * 16 + (l >> 4) * 4 + r;
      int base = row * 193 + w * 48 + (l & 15) * 3;
      mK[base+0] = K[rt*4+r][0]; mK[base+1] = K[rt*4+r][1]; mK[base+2] = K[rt*4+r][2];
    }
  __syncthreads();
  float* aux = (float*)(sm + 49408);   // after 64*193*4 B; stride 17 words
  {
    int row = tid >> 2, q = tid & 3;
    float t0 = 0.f, t1 = 0.f, t2 = 0.f, t3 = 0.f;
    const float* src = mK + row * 193 + q * 48;
    for (int s = 0; s < 48; s++){
      float v = src[s];
      t3 = __builtin_amdgcn_fmed3f(t2, t3, v);
      t2 = __builtin_amdgcn_fmed3f(t1, t2, v);
      t1 = __builtin_amdgcn_fmed3f(t0, t1, v);
      t0 = fmaxf(t0, v);
    }
    float* d = aux + row * 17 + q * 4;
    d[0] = t0; d[1] = t1; d[2] = t2; d[3] = t3;
  }
  __syncthreads();
  if (tid < 64){
    float u0=0.f,u1=0.f,u2=0.f,u3=0.f,u4=0.f,u5=0.f,u6=0.f,u7=0.f;
    const float* srcp = aux + tid * 17;
    #pragma unroll
    for (int s = 0; s < 16; s++){
      float v = srcp[s];
      u7 = __builtin_amdgcn_fmed3f(u6, u7, v);
      u6 = __builtin_amdgcn_fmed3f(u5, u6, v);
      u5 = __builtin_amdgcn_fmed3f(u4, u5, v);
      u4 = __builtin_amdgcn_fmed3f(u3, u4, v);
      u3 = __builtin_amdgcn_fmed3f(u2, u3, v);
      u2 = __builtin_amdgcn_fmed3f(u1, u2, v);
      u1 = __builtin_amdgcn_fmed3f(u0, u1, v);
      u0 = fmaxf(u0, v);
    }
    int* d = idx8 + ((size_t)(b * N + m0 + tid)) * 8;
    d[0]=2047-(int)(f2u(u0)&2047u); d[1]=2047-(int)(f2u(u1)&2047u);
    d[2]=2047-(int)(f2u(u2)&2047u); d[3]=2047-(int)(f2u(u3)&2047u);
    d[4]=2047-(int)(f2u(u4)&2047u); d[5]=2047-(int)(f2u(u5)&2047u);
    d[6]=2047-(int)(f2u(u6)&2047u); d[7]=2047-(int)(f2u(u7)&2047u);
  }
}

// ---------- k_rerank: exact fp32 pd over 8 candidates, pair-parallel (2 rows/wave) ----------
__global__ __launch_bounds__(256) void k_rerank(const float* __restrict__ xT,
    const float* __restrict__ sq4, const int* __restrict__ idx8, int* __restrict__ idx3)
{
  int w = threadIdx.x >> 6, l = threadIdx.x & 63;
  int h = l >> 5, lh = l & 31;
  int wv = blockIdx.x * 4 + w;
  #pragma unroll
  for (int rr = 0; rr < 2; rr++){
    int row = wv * 2 + rr;
    int b = row >> 11;
    const float* xm = xT + (size_t)row * 256 + lh * 8;
    f4 xm0 = *(const f4*)xm;
    f4 xm1 = *(const f4*)(xm + 4);
    const int* cb = idx8 + (size_t)row * 8;
    int nn[8];
    #pragma unroll
    for (int c2 = 0; c2 < 8; c2++) nn[c2] = cb[c2];
    f4 a0[4], a1[4];
    #pragma unroll
    for (int j = 0; j < 4; j++){
      int n = nn[2*j + h];
      const float* xn = xT + ((size_t)(b * N + n)) * 256 + lh * 8;
      a0[j] = *(const f4*)xn;
      a1[j] = *(const f4*)(xn + 4);
    }
    float v0=-3e38f, v1=v0, v2=v0; int i0=0x7fffffff, i1=i0, i2=i0;
    #pragma unroll
    for (int j = 0; j < 4; j++){
      float s = ((xm0[0]*a0[j][0] + xm0[1]*a0[j][1]) + (xm0[2]*a0[j][2] + xm0[3]*a0[j][3]))
              + ((xm1[0]*a1[j][0] + xm1[1]*a1[j][1]) + (xm1[2]*a1[j][2] + xm1[3]*a1[j][3]));
      #pragma unroll
      for (int d = 1; d < 32; d <<= 1) s += __shfl_xor(s, d, 64);
      float so = __shfl_xor(s, 32, 64);
      float pe = h ? so : s;
      float po = h ? s : so;
      int ne = nn[2*j], no = nn[2*j+1];
      f4 s4e = *(const f4*)(sq4 + ((size_t)(b * N + ne)) * 4);
      f4 s4o = *(const f4*)(sq4 + ((size_t)(b * N + no)) * 4);
      float ve = 2.f * pe - ((s4e[0] + s4e[1]) + (s4e[2] + s4e[3]));
      float vo = 2.f * po - ((s4o[0] + s4o[1]) + (s4o[2] + s4o[3]));
      ins3(ve, ne, v0, v1, v2, i0, i1, i2);
      ins3(vo, no, v0, v1, v2, i0, i1, i2);
    }
    if (l == 0){
      size_t ob = (size_t)row * 3;
      idx3[ob] = i0; idx3[ob+1] = i1; idx3[ob+2] = i2;
    }
  }
}

// ---------- k_ut1 (MFMA, ct-split for occupancy): rows 0..255 -> u, 256..383 -> t1 ----------
__global__ __launch_bounds__(256, 2) void k_ut1(const float* __restrict__ Ws1,
    const float* __restrict__ Wt1, const float* __restrict__ bt1,
    const unsigned short* __restrict__ xhT,
    unsigned short* __restrict__ u_ws, unsigned short* __restrict__ t1_ws)
{
  __shared__ __align__(16) unsigned short A[64 * 256];
  int wg = blockIdx.x;
  int wid = (wg & 7) * 384 + (wg >> 3);   // chunked XCD swizzle (3072 blocks)
  int q24 = wid % 24;                     // 6 mb x 4 ct share one x p-tile (L2)
  int mb = q24 % 6, ct = q24 / 6;
  int pt = wid / 24;
  int m0 = mb * 64, p0 = pt * 256;
  int tid = threadIdx.x, w = tid >> 6, l = tid & 63;
  #pragma unroll
  for (int i = 0; i < 8; i++){
    int flat = i * 256 + tid;
    int m = flat >> 5, c = flat & 31;
    int mg = m0 + m;
    const float* srcp;
    if (mg < 128)      srcp = Ws1 + (size_t)mg * 512 + c * 8;
    else if (mg < 256) srcp = Ws1 + (size_t)(mg - 128) * 512 + 256 + c * 8;
    else               srcp = Wt1 + (size_t)(mg - 256) * 256 + c * 8;
    f4 v0 = *(const f4*)srcp, v1 = *(const f4*)(srcp + 4);
    u16x8 h;
    h[0]=f2bf(v0[0]); h[1]=f2bf(v0[1]); h[2]=f2bf(v0[2]); h[3]=f2bf(v0[3]);
    h[4]=f2bf(v1[0]); h[5]=f2bf(v1[1]); h[6]=f2bf(v1[2]); h[7]=f2bf(v1[3]);
    *(u16x8*)(A + m * 256 + ((c ^ (m & 7)) << 3)) = h;
  }
  __syncthreads();
  bf16x8 af[4][8];
  #pragma unroll
  for (int rt = 0; rt < 4; rt++)
    #pragma unroll
    for (int ks = 0; ks < 8; ks++){
      int m = rt * 16 + (l & 15);
      int ch = ks * 4 + (l >> 4);
      af[rt][ks] = *(const bf16x8*)((const char*)A + m * 512 + ((ch ^ (m & 7)) << 4));
    }
  bool isU = (m0 < 256);
  f4 bias[4];
  if (!isU){
    #pragma unroll
    for (int rt = 0; rt < 4; rt++)
      bias[rt] = *(const f4*)(bt1 + (m0 - 256) + rt * 16 + (l >> 4) * 4);
  }
  {
    int p = p0 + ct * 64 + w * 16 + (l & 15);
    const unsigned short* bp = xhT + (size_t)p * 256 + (l >> 4) * 8;
    f32x4 acc[4];
    f32x4 z = {0.f, 0.f, 0.f, 0.f};
    #pragma unroll
    for (int rt = 0; rt < 4; rt++) acc[rt] = z;
    #pragma unroll
    for (int ks = 0; ks < 8; ks++){
      bf16x8 bv = *(const bf16x8*)(bp + ks * 32);
      #pragma unroll
      for (int rt = 0; rt < 4; rt++)
        acc[rt] = __builtin_amdgcn_mfma_f32_16x16x32_bf16(af[rt][ks], bv, acc[rt], 0, 0, 0);
    }
    if (isU){
      #pragma unroll
      for (int rt = 0; rt < 4; rt++){
        u16x4 h;
        h[0]=f2bf(acc[rt][0]); h[1]=f2bf(acc[rt][1]); h[2]=f2bf(acc[rt][2]); h[3]=f2bf(acc[rt][3]);
        *(u16x4*)(u_ws + (size_t)p * 256 + m0 + rt * 16 + (l >> 4) * 4) = h;
      }
    } else {
      #pragma unroll
      for (int rt = 0; rt < 4; rt++){
        u16x4 h;
        h[0]=f2bf(fmaxf(acc[rt][0] + bias[rt][0], 0.f));
        h[1]=f2bf(fmaxf(acc[rt][1] + bias[rt][1], 0.f));
        h[2]=f2bf(fmaxf(acc[rt][2] + bias[rt][2], 0.f));
        h[3]=f2bf(fmaxf(acc[rt][3] + bias[rt][3], 0.f));
        *(u16x4*)(t1_ws + (size_t)p * 128 + (m0 - 256) + rt * 16 + (l >> 4) * 4) = h;
      }
    }
  }
}

// ---------- k_te (fused independent): blocks 0..511 = t2 grouped conv; 512..1023 = e1 gather+s1+s2 ----------
__global__ __launch_bounds__(256) void k_te(const unsigned short* __restrict__ t1_ws,
    const float* __restrict__ Wt2, const float* __restrict__ bt2,
    unsigned short* __restrict__ t2_ws,
    const unsigned short* __restrict__ u_ws, const int* __restrict__ idx_ws,
    const float* __restrict__ bs1, const float* __restrict__ Ws2,
    const float* __restrict__ bs2, unsigned short* __restrict__ s2_ws)
{
  __shared__ float w2[1536];
  __shared__ float b2[128];
  __shared__ float sb1[128], sb2[128], sw2[512];
  int tid = threadIdx.x;
  if (blockIdx.x < 512){
    for (int i = tid; i < 1536; i += 256) w2[i] = Wt2[i];
    if (tid < 128) b2[tid] = bt2[tid];
    __syncthreads();
    int p = blockIdx.x * 64 + (tid >> 2);
    int q = tid & 3;
    int n = p & (N - 1);
    const unsigned short* rp = t1_ws + (size_t)p * 128;
    u16x8 zz = {0,0,0,0,0,0,0,0};
    #pragma unroll
    for (int g8 = 0; g8 < 4; g8++){
      int ch0 = q*32 + g8*8;
      u16x8 vm1 = (n > 0)     ? *(const u16x8*)(rp - 128 + ch0) : zz;
      u16x8 v0  =               *(const u16x8*)(rp + ch0);
      u16x8 vp1 = (n < N - 1) ? *(const u16x8*)(rp + 128 + ch0) : zz;
      float fm1[8], f0[8], fp1[8];
      #pragma unroll
      for (int e = 0; e < 8; e++){ fm1[e]=bf2f(vm1[e]); f0[e]=bf2f(v0[e]); fp1[e]=bf2f(vp1[e]); }
      u16x8 o;
      #pragma unroll
      for (int j = 0; j < 8; j++){
        int wch = ch0 + j, gb = j & ~3;
        float acc = b2[wch];
        #pragma unroll
        for (int i = 0; i < 4; i++){
          acc += w2[wch*12 + i*3 + 0] * fm1[gb + i];
          acc += w2[wch*12 + i*3 + 1] * f0[gb + i];
          acc += w2[wch*12 + i*3 + 2] * fp1[gb + i];
        }
        o[j] = f2bf(fmaxf(acc, 0.f));
      }
      *(u16x8*)(t2_ws + (size_t)p * 128 + ch0) = o;
    }
  } else {
    if (tid < 128){ sb1[tid] = bs1[tid]; sb2[tid] = bs2[tid]; }
    sw2[tid] = Ws2[tid]; sw2[tid+256] = Ws2[tid+256];
    __syncthreads();
    int p0 = (blockIdx.x - 512) * 64;
    #pragma unroll
    for (int rep = 0; rep < 3; rep++){
      int task = rep*256 + tid;
      int r = task >> 2, q = task & 3;
      int pl = r / 3, k = r - pl*3;
      int p = p0 + pl;
      int b = p >> 11;
      int m = idx_ws[(size_t)p*3 + k] & (N - 1);
      const unsigned short* ua = u_ws + ((size_t)(b*N + m))*256 + q*32;
      const unsigned short* ub = u_ws + ((size_t)p)*256 + 128 + q*32;
      float s1v[32];
      #pragma unroll
      for (int jj = 0; jj < 4; jj++){
        u16x8 a  = *(const u16x8*)(ua + jj*8);
        u16x8 cbv = *(const u16x8*)(ub + jj*8);
        #pragma unroll
        for (int e = 0; e < 8; e++){
          int j = jj*8 + e;
          s1v[j] = fmaxf(bf2f(a[e]) + bf2f(cbv[e]) + sb1[q*32 + j], 0.f);
        }
      }
      #pragma unroll
      for (int jj = 0; jj < 4; jj++){
        u16x8 o;
        #pragma unroll
        for (int e = 0; e < 8; e++){
          int j = jj*8 + e;
          int ch = q*32 + j, gb = j & ~3;
          float a2 = sb2[ch] + sw2[ch*4+0]*s1v[gb]   + sw2[ch*4+1]*s1v[gb+1]
                             + sw2[ch*4+2]*s1v[gb+2] + sw2[ch*4+3]*s1v[gb+3];
          o[e] = f2bf(fmaxf(a2, 0.f));
        }
        *(u16x8*)(s2_ws + ((size_t)k * BN + p) * 128 + q*32 + jj*8) = o;
      }
    }
  }
}

// ---------- k_e2f (fused, ct-split for occupancy): s3_k = Ws3.s2_k, tout = Wt3.t2 ;
// out = relu(max_k(s3)+bs3 + tout+bt3 + x) ----------
__global__ __launch_bounds__(256, 2) void k_e2f(const unsigned short* __restrict__ s2_ws,
    const unsigned short* __restrict__ t2_ws,
    const float* __restrict__ Ws3, const float* __restrict__ bs3,
    const float* __restrict__ Wt3, const float* __restrict__ bt3,
    const float* __restrict__ x, float* __restrict__ out)
{
  __shared__ __align__(16) unsigned short As[64 * 128];
  __shared__ __align__(16) unsigned short At[64 * 128];
  int wg = blockIdx.x;
  int wid = (wg & 7) * 256 + (wg >> 3);   // 2048 blocks, bijective XCD swizzle
  int mb = wid & 3, pc = wid >> 2;
  int pt = pc >> 2, ct = pc & 3;
  int m0 = mb * 64, p0 = pt * 256;
  int tid = threadIdx.x, w = tid >> 6, l = tid & 63;
  #pragma unroll
  for (int i = 0; i < 4; i++){
    int flat = i * 256 + tid;
    int m = flat >> 4, c = flat & 15;
    {
      const float* srcp = Ws3 + (size_t)(m0 + m) * 128 + c * 8;
      f4 v0 = *(const f4*)srcp, v1 = *(const f4*)(srcp + 4);
      u16x8 h;
      h[0]=f2bf(v0[0]); h[1]=f2bf(v0[1]); h[2]=f2bf(v0[2]); h[3]=f2bf(v0[3]);
      h[4]=f2bf(v1[0]); h[5]=f2bf(v1[1]); h[6]=f2bf(v1[2]); h[7]=f2bf(v1[3]);
      *(u16x8*)(As + m * 128 + ((c ^ (m & 7)) << 3)) = h;
    }
    {
      const float* srcp = Wt3 + (size_t)(m0 + m) * 128 + c * 8;
      f4 v0 = *(const f4*)srcp, v1 = *(const f4*)(srcp + 4);
      u16x8 h;
      h[0]=f2bf(v0[0]); h[1]=f2bf(v0[1]); h[2]=f2bf(v0[2]); h[3]=f2bf(v0[3]);
      h[4]=f2bf(v1[0]); h[5]=f2bf(v1[1]); h[6]=f2bf(v1[2]); h[7]=f2bf(v1[3]);
      *(u16x8*)(At + m * 128 + ((c ^ (m & 7)) << 3)) = h;
    }
  }
  __syncthreads();
  bf16x8 afs[4][4], aft[4][4];
  #pragma unroll
  for (int rt = 0; rt < 4; rt++)
    #pragma unroll
    for (int ks = 0; ks < 4; ks++){
      int m = rt * 16 + (l & 15);
      int ch = ks * 4 + (l >> 4);
      afs[rt][ks] = *(const bf16x8*)((const char*)As + m * 256 + ((ch ^ (m & 7)) << 4));
      aft[rt][ks] = *(const bf16x8*)((const char*)At + m * 256 + ((ch ^ (m & 7)) << 4));
    }
  f4 biasS[4], biasT[4];
  #pragma unroll
  for (int rt = 0; rt < 4; rt++){
    biasS[rt] = *(const f4*)(bs3 + m0 + rt * 16 + (l >> 4) * 4);
    biasT[rt] = *(const f4*)(bt3 + m0 + rt * 16 + (l >> 4) * 4);
  }
  {
    int p = p0 + ct * 64 + w * 16 + (l & 15);
    int b = p >> 11, n = p & (N - 1);
    const unsigned short* bp0 = s2_ws + ((size_t)(0 * BN + p)) * 128 + (l >> 4) * 8;
    const unsigned short* bp1 = s2_ws + ((size_t)(1 * BN + p)) * 128 + (l >> 4) * 8;
    const unsigned short* bp2 = s2_ws + ((size_t)(2 * BN + p)) * 128 + (l >> 4) * 8;
    const unsigned short* bpt = t2_ws + ((size_t)p) * 128 + (l >> 4) * 8;
    f32x4 acc[4][4];
    f32x4 z = {0.f, 0.f, 0.f, 0.f};
    #pragma unroll
    for (int rt = 0; rt < 4; rt++){ acc[rt][0]=z; acc[rt][1]=z; acc[rt][2]=z; acc[rt][3]=z; }
    #pragma unroll
    for (int ks = 0; ks < 4; ks++){
      bf16x8 bv0 = *(const bf16x8*)(bp0 + ks * 32);
      bf16x8 bv1 = *(const bf16x8*)(bp1 + ks * 32);
      bf16x8 bv2 = *(const bf16x8*)(bp2 + ks * 32);
      bf16x8 bvt = *(const bf16x8*)(bpt + ks * 32);
      #pragma unroll
      for (int rt = 0; rt < 4; rt++){
        acc[rt][0] = __builtin_amdgcn_mfma_f32_16x16x32_bf16(afs[rt][ks], bv0, acc[rt][0], 0, 0, 0);
        acc[rt][1] = __builtin_amdgcn_mfma_f32_16x16x32_bf16(afs[rt][ks], bv1, acc[rt][1], 0, 0, 0);
        acc[rt][2] = __builtin_amdgcn_mfma_f32_16x16x32_bf16(afs[rt][ks], bv2, acc[rt][2], 0, 0, 0);
        acc[rt][3] = __builtin_amdgcn_mfma_f32_16x16x32_bf16(aft[rt][ks], bvt, acc[rt][3], 0, 0, 0);
      }
    }
    #pragma unroll
    for (int rt = 0; rt < 4; rt++){
      int mbase = m0 + rt * 16 + (l >> 4) * 4;
      #pragma unroll
      for (int r = 0; r < 4; r++){
        float sout = fmaxf(fmaxf(acc[rt][0][r], acc[rt][1][r]), acc[rt][2][r]) + biasS[rt][r];
        float tout = acc[rt][3][r] + biasT[rt][r];
        size_t ob = ((size_t)(b * 256 + mbase + r)) * N + n;
        out[ob] = fmaxf(sout + tout + x[ob], 0.f);
      }
    }
  }
}

extern "C" void kernel_launch(void* const* d_in, const int* in_sizes, int n_in,
                              void* d_out, int out_size, void* d_ws, size_t ws_size,
                              hipStream_t stream)
{
  const float* x   = (const float*)d_in[0];
  const float* Wt1 = (const float*)d_in[1];
  const float* bt1 = (const float*)d_in[2];
  const float* Wt2 = (const float*)d_in[3];
  const float* bt2 = (const float*)d_in[4];
  const float* Wt3 = (const float*)d_in[5];
  const float* bt3 = (const float*)d_in[6];
  const float* Ws1 = (const float*)d_in[7];
  const float* bs1 = (const float*)d_in[8];
  const float* Ws2 = (const float*)d_in[9];
  const float* bs2 = (const float*)d_in[10];
  const float* Ws3 = (const float*)d_in[11];
  const float* bs3 = (const float*)d_in[12];
  float* out = (float*)d_out;

  // workspace: [idx3 384K + spare -> 524288][pool 58.72MB time-sliced]
  // phase1 (knn): xT @0 (33.55M) | xhT @33554432 (16.78M) | idx8 @50331648 (1.05M) | sq4 @51380224 (512K)
  // phase2:       u @0 (16.78M) | t1 @16777216 (8.39M) | t2 @25165824 (8.39M) | s2 @33554432 (25.17M)
  // ordering (CRITICAL for aliasing): k_rerank (last xT/idx8/sq4 reader) BEFORE k_ut1 (writes u/t1 over xT);
  //           k_ut1 (last xhT reader) BEFORE k_te's e1 branch (writes s2 over xhT/idx8/sq4).
  char* ws = (char*)d_ws;
  if (ws_size < 59244544u) return;   // loud, diagnosable failure (output stays poisoned)
  int*   idx3 = (int*)ws;
  char*  P    = ws + 524288;
  float*          xT    = (float*)P;
  unsigned short* xhT   = (unsigned short*)(P + 33554432);
  int*            idx8  = (int*)(P + 50331648);
  float*          sq4   = (float*)(P + 51380224);
  unsigned short* u_ws  = (unsigned short*)P;
  unsigned short* t1_ws = (unsigned short*)(P + 16777216);
  unsigned short* t2_ws = (unsigned short*)(P + 25165824);
  unsigned short* s2_ws = (unsigned short*)(P + 33554432);

  k_cvt   <<<2048, 256, 0, stream>>>(x, xhT, xT, sq4);
  k_pd    <<<512, 256, 0, stream>>>(xhT, sq4, idx8);
  k_rerank<<<4096, 256, 0, stream>>>(xT, sq4, idx8, idx3);
  k_ut1   <<<3072, 256, 0, stream>>>(Ws1, Wt1, bt1, xhT, u_ws, t1_ws);
  k_te    <<<1024, 256, 0, stream>>>(t1_ws, Wt2, bt2, t2_ws, u_ws, idx3, bs1, Ws2, bs2, s2_ws);
  k_e2f   <<<2048, 256, 0, stream>>>(s2_ws, t2_ws, Ws3, bs3, Wt3, bt3, x, out);
}